// Round 6
// baseline (322.324 us; speedup 1.0000x reference)
//
#include <hip/hip_runtime.h>
#include <math.h>

// CSConv: grouped conv (groups=256, Cout=512, K=3, pad=1) + bias + BN(inference) + SiLU
// x: (16, 256, 80, 80) f32; w: (512, 1, 3, 3); per-channel b/gamma/beta/mean/var (512)
// out: (16, 512, 80, 80) f32. Output channel co uses input channel co>>1.
//
// Direct-from-global version (no LDS, no barriers): one block per (b,g) plane,
// 320 threads x 5 iterations = 1600 quads. Each thread reads its 3x6 input
// window straight from global (aligned float4 + 2 clamped scalars per row);
// the 25.6 KB plane is L1/L2-resident so halo overlap is absorbed by cache.
// Boundary handling is branchless: clamped addresses + value masks, preserving
// the exact window mapping of the verified Round-2 kernel.

#define CS_B    16
#define CS_CIN  256
#define CS_COUT 512
#define CS_H    80
#define CS_W    80
#define BN_EPS  1e-5f
#define NQ      (CS_H * CS_W / 4)   // 1600 quads per plane
#define QPR     (CS_W / 4)          // 20 quads per row
#define THREADS 320                 // 1600 / 320 = 5 exact iterations

__global__ __launch_bounds__(THREADS) void csconv_kernel(
    const float* __restrict__ x,
    const float* __restrict__ wgt,
    const float* __restrict__ bias,
    const float* __restrict__ gamma,
    const float* __restrict__ beta,
    const float* __restrict__ mean,
    const float* __restrict__ var,
    float* __restrict__ out)
{
    const int plane = blockIdx.x;            // b * 256 + g
    const int g     = plane & (CS_CIN - 1);
    const int tid   = threadIdx.x;

    const float* xp = x + (size_t)plane * (CS_H * CS_W);

    const int co0 = 2 * g;
    const int co1 = co0 + 1;

    float k0[9], k1[9];
#pragma unroll
    for (int t = 0; t < 9; ++t) {
        k0[t] = wgt[co0 * 9 + t];
        k1[t] = wgt[co1 * 9 + t];
    }
    // Fold bias into BN shift: y = conv*s + (bias*s + beta - mean*s)
    const float s0 = gamma[co0] * rsqrtf(var[co0] + BN_EPS);
    const float s1 = gamma[co1] * rsqrtf(var[co1] + BN_EPS);
    const float t0 = beta[co0] + (bias[co0] - mean[co0]) * s0;
    const float t1 = beta[co1] + (bias[co1] - mean[co1]) * s1;

    // out plane pair: b*512 + 2g = 2*plane
    float* op0 = out + (size_t)(2 * plane) * (CS_H * CS_W);
    float* op1 = op0 + CS_H * CS_W;

    for (int q = tid; q < NQ; q += THREADS) {
        const int r  = q / QPR;
        const int c4 = (q - r * QPR) * 4;

        const float* rm = xp + r * CS_W;
        const float* rt = (r > 0)          ? rm - CS_W : rm;  // clamped addr
        const float* rb = (r < CS_H - 1)   ? rm + CS_W : rm;
        const int cl = (c4 > 0)            ? c4 - 1 : 0;
        const int cr = (c4 < CS_W - 4)     ? c4 + 4 : CS_W - 1;

        // 3 rows x (aligned float4 + left scalar + right scalar)
        float4 m0 = *(const float4*)&rt[c4]; float l0 = rt[cl]; float r0 = rt[cr];
        float4 m1 = *(const float4*)&rm[c4]; float l1 = rm[cl]; float r1 = rm[cr];
        float4 m2 = *(const float4*)&rb[c4]; float l2 = rb[cl]; float r2 = rb[cr];

        // Branchless boundary masks: zero out-of-image values.
        const bool mt = (r > 0), mb = (r < CS_H - 1), ml = (c4 > 0), mr = (c4 < CS_W - 4);
        if (!mt) { m0 = make_float4(0.f, 0.f, 0.f, 0.f); l0 = 0.f; r0 = 0.f; }
        if (!mb) { m2 = make_float4(0.f, 0.f, 0.f, 0.f); l2 = 0.f; r2 = 0.f; }
        l0 = ml ? l0 : 0.f; l1 = ml ? l1 : 0.f; l2 = ml ? l2 : 0.f;
        r0 = mr ? r0 : 0.f; r1 = mr ? r1 : 0.f; r2 = mr ? r2 : 0.f;

        // v[row][0..5] = input cols c4-1 .. c4+4 (identical window to Round-2)
        float v[3][6] = {
            { l0, m0.x, m0.y, m0.z, m0.w, r0 },
            { l1, m1.x, m1.y, m1.z, m1.w, r1 },
            { l2, m2.x, m2.y, m2.z, m2.w, r2 },
        };

        float acc0[4] = {0.f, 0.f, 0.f, 0.f};
        float acc1[4] = {0.f, 0.f, 0.f, 0.f};
#pragma unroll
        for (int kh = 0; kh < 3; ++kh) {
            float w00 = k0[kh * 3 + 0], w01 = k0[kh * 3 + 1], w02 = k0[kh * 3 + 2];
            float w10 = k1[kh * 3 + 0], w11 = k1[kh * 3 + 1], w12 = k1[kh * 3 + 2];
#pragma unroll
            for (int j = 0; j < 4; ++j) {
                acc0[j] = fmaf(v[kh][j], w00, fmaf(v[kh][j+1], w01, fmaf(v[kh][j+2], w02, acc0[j])));
                acc1[j] = fmaf(v[kh][j], w10, fmaf(v[kh][j+1], w11, fmaf(v[kh][j+2], w12, acc1[j])));
            }
        }

        float4 y0, y1;
        float* y0p = &y0.x;
        float* y1p = &y1.x;
#pragma unroll
        for (int j = 0; j < 4; ++j) {
            float a0 = fmaf(acc0[j], s0, t0);
            float a1 = fmaf(acc1[j], s1, t1);
            y0p[j] = __fdividef(a0, 1.0f + __expf(-a0));
            y1p[j] = __fdividef(a1, 1.0f + __expf(-a1));
        }
        ((float4*)op0)[q] = y0;
        ((float4*)op1)[q] = y1;
    }
}

extern "C" void kernel_launch(void* const* d_in, const int* in_sizes, int n_in,
                              void* d_out, int out_size, void* d_ws, size_t ws_size,
                              hipStream_t stream) {
    const float* x     = (const float*)d_in[0];
    const float* wgt   = (const float*)d_in[1];
    const float* bias  = (const float*)d_in[2];
    const float* gamma = (const float*)d_in[3];
    const float* beta  = (const float*)d_in[4];
    const float* mean  = (const float*)d_in[5];
    const float* var   = (const float*)d_in[6];
    float* out = (float*)d_out;

    dim3 grid(CS_B * CS_CIN);
    dim3 block(THREADS);
    csconv_kernel<<<grid, block, 0, stream>>>(x, wgt, bias, gamma, beta, mean, var, out);
}